// Round 1
// baseline (942.483 us; speedup 1.0000x reference)
//
#include <hip/hip_runtime.h>

// CausalTrajectoryPrediction: 256 independent per-node GEMV chains.
// N=256, H=1024, M=256. Memory-bound: ~0.8 GB fp32 weight streaming
// (stage-3 reads only the live half of W3). One block per node,
// 1024 threads = 16 waves, wave handles row-pairs with float4 loads.

#define NN 256
#define HH 1024
#define MM 256

__device__ __forceinline__ float dot4(float4 a, float4 b) {
    return fmaf(a.x, b.x, fmaf(a.y, b.y, fmaf(a.z, b.z, a.w * b.w)));
}

// p0 = this lane's partial of row A, p1 = partial of row B (64 lanes each).
// After: all low lanes (0-31) hold total(A), all high lanes hold total(B).
// Costs 6 shuffles for TWO rows instead of 12.
__device__ __forceinline__ float reduce_pair(float p0, float p1, int lane) {
    float send = (lane < 32) ? p1 : p0;
    float recv = __shfl_xor(send, 32);
    float v = ((lane < 32) ? p0 : p1) + recv;
    v += __shfl_xor(v, 16);
    v += __shfl_xor(v, 8);
    v += __shfl_xor(v, 4);
    v += __shfl_xor(v, 2);
    v += __shfl_xor(v, 1);
    return v;
}

__global__ __launch_bounds__(1024) void ctp_kernel(
    const float* __restrict__ x,   // [N]
    const float* __restrict__ W1,  // [N,H,N]
    const float* __restrict__ W2,  // [N,M,H]
    const float* __restrict__ W3,  // [N,H,M+N]
    const float* __restrict__ b3,  // [N,H]
    const float* __restrict__ W4,  // [N,1,H]
    const float* __restrict__ b4,  // [N,1]
    float* __restrict__ out)       // [N]
{
    const int n    = blockIdx.x;
    const int tid  = threadIdx.x;
    const int lane = tid & 63;
    const int wave = tid >> 6;        // 0..15
    const int sub  = lane >> 5;       // which half-wave -> which row of the pair
    const bool head = (lane & 31) == 0;

    __shared__ __align__(16) float s_x[NN];
    __shared__ __align__(16) float s_v1[HH];
    __shared__ __align__(16) float s_v2[MM];
    __shared__ __align__(16) float s_v3[HH];
    __shared__ float s_red[16];

    if (tid < NN) {
        float v = x[tid];
        s_x[tid] = (tid == n) ? 0.0f : v;   // inputs_1 row n: x with x[n] zeroed
    }
    __syncthreads();

    // ---- Stage 1: v1 = relu(W1[n] @ x_masked), W1[n]: [H=1024, N=256] ----
    {
        const float* Wn = W1 + (size_t)n * (HH * NN);
        const float4 xv = ((const float4*)s_x)[lane];   // lane's 4 elements of x
        const int hbase = wave * 64;                    // 64 rows per wave
        for (int r = 0; r < 64; r += 4) {
            const float* r0 = Wn + (size_t)(hbase + r) * NN;
            float4 a = ((const float4*)(r0         ))[lane];
            float4 b = ((const float4*)(r0 +     NN))[lane];
            float4 c = ((const float4*)(r0 + 2 * NN))[lane];
            float4 d = ((const float4*)(r0 + 3 * NN))[lane];
            float v01 = reduce_pair(dot4(a, xv), dot4(b, xv), lane);
            float v23 = reduce_pair(dot4(c, xv), dot4(d, xv), lane);
            if (head) {
                s_v1[hbase + r + sub]     = fmaxf(v01, 0.0f);
                s_v1[hbase + r + 2 + sub] = fmaxf(v23, 0.0f);
            }
        }
    }
    __syncthreads();

    // ---- Stage 2: v2 = relu(W2[n] @ v1), W2[n]: [M=256, H=1024] ----
    {
        const float* Wn = W2 + (size_t)n * (MM * HH);
        float4 v1c[4];
        #pragma unroll
        for (int k = 0; k < 4; ++k) v1c[k] = ((const float4*)s_v1)[lane + 64 * k];
        const int mbase = wave * 16;                    // 16 rows per wave
        for (int r = 0; r < 16; r += 2) {
            const float* r0 = Wn + (size_t)(mbase + r) * HH;
            float p0 = 0.0f, p1 = 0.0f;
            #pragma unroll
            for (int k = 0; k < 4; ++k) {
                float4 w0 = ((const float4*)(r0     ))[lane + 64 * k];
                float4 w1 = ((const float4*)(r0 + HH))[lane + 64 * k];
                p0 += dot4(w0, v1c[k]);
                p1 += dot4(w1, v1c[k]);
            }
            float v = reduce_pair(p0, p1, lane);
            if (head) s_v2[mbase + r + sub] = fmaxf(v, 0.0f);
        }
    }
    __syncthreads();

    // ---- Stage 3: v3 = relu(W3[n][:, :M] @ v2 + W3[n][:, M+n]*x[n] + b3[n]) ----
    // z = concat([v2, x*eye row n]); the eye part is zero except col M+n, so
    // we read only 256 of 512 columns + one scalar per row (wave-uniform -> s_load).
    {
        const float* Wn  = W3 + (size_t)n * (HH * (MM + NN));
        const float* b3n = b3 + (size_t)n * HH;
        const float xn = x[n];
        const float4 v2v = ((const float4*)s_v2)[lane];
        const int hbase = wave * 64;
        for (int r = 0; r < 64; r += 4) {
            const float* r0 = Wn + (size_t)(hbase + r) * (MM + NN);
            float4 a = ((const float4*)(r0       ))[lane];
            float4 b = ((const float4*)(r0 +  512))[lane];
            float4 c = ((const float4*)(r0 + 1024))[lane];
            float4 d = ((const float4*)(r0 + 1536))[lane];
            float e0 = fmaf(r0[MM + n],        xn, b3n[hbase + r + 0]);
            float e1 = fmaf(r0[512 + MM + n],  xn, b3n[hbase + r + 1]);
            float e2 = fmaf(r0[1024 + MM + n], xn, b3n[hbase + r + 2]);
            float e3 = fmaf(r0[1536 + MM + n], xn, b3n[hbase + r + 3]);
            float v01 = reduce_pair(dot4(a, v2v), dot4(b, v2v), lane);
            float v23 = reduce_pair(dot4(c, v2v), dot4(d, v2v), lane);
            float add01 = (lane < 32) ? e0 : e1;
            float add23 = (lane < 32) ? e2 : e3;
            if (head) {
                s_v3[hbase + r + sub]     = fmaxf(v01 + add01, 0.0f);
                s_v3[hbase + r + 2 + sub] = fmaxf(v23 + add23, 0.0f);
            }
        }
    }
    __syncthreads();

    // ---- Stage 4: out[n] = relu(dot(W4[n], v3) + b4[n]) ----
    {
        const float* Wn = W4 + (size_t)n * HH;
        float p = Wn[tid] * s_v3[tid];
        p += __shfl_xor(p, 32);
        p += __shfl_xor(p, 16);
        p += __shfl_xor(p, 8);
        p += __shfl_xor(p, 4);
        p += __shfl_xor(p, 2);
        p += __shfl_xor(p, 1);
        if (lane == 0) s_red[wave] = p;
        __syncthreads();
        if (wave == 0) {
            float v = (lane < 16) ? s_red[lane] : 0.0f;
            v += __shfl_xor(v, 8);
            v += __shfl_xor(v, 4);
            v += __shfl_xor(v, 2);
            v += __shfl_xor(v, 1);
            if (lane == 0) out[n] = fmaxf(v + b4[n], 0.0f);
        }
    }
}

extern "C" void kernel_launch(void* const* d_in, const int* in_sizes, int n_in,
                              void* d_out, int out_size, void* d_ws, size_t ws_size,
                              hipStream_t stream) {
    const float* x  = (const float*)d_in[0];
    const float* W1 = (const float*)d_in[1];
    const float* W2 = (const float*)d_in[2];
    const float* W3 = (const float*)d_in[3];
    const float* b3 = (const float*)d_in[4];
    const float* W4 = (const float*)d_in[5];
    const float* b4 = (const float*)d_in[6];
    float* out = (float*)d_out;
    hipLaunchKernelGGL(ctp_kernel, dim3(NN), dim3(1024), 0, stream,
                       x, W1, W2, W3, b3, W4, b4, out);
}